// Round 1
// baseline (460.602 us; speedup 1.0000x reference)
//
#include <hip/hip_runtime.h>

#define BT 10
#define CC 384
#define DH 64
#define CTXC 128
#define NS 4
#define SCALE_F 0.125f

// vout offsets (floats) per stage, aout base
#define VOFF0 0
#define VOFF1 24576000
#define VOFF2 30720000
#define VOFF3 32256000
#define AOUT_OFF 32640000
// sim buffer per-stage offsets within one partial buffer (floats)
#define SIM_TOT 85000

struct Params {
  const float* fmap0; const float* fmap1; const float* fmap2; const float* fmap3;
  const float* pos0;  const float* pos1;  const float* pos2;  const float* pos3;
  const float* audio0;const float* audio1;const float* audio2;const float* audio3;
  const float* ctx_proj_w; const float* ctx_proj_b; const float* pos_emb;
  const float* qk_w; const float* ctx_qk_w; const float* v_w; const float* ctx_v_w;
  const float* out_w; const float* out_b; const float* ctx_out_w; const float* ctx_out_b;
  float* out;
  float* r;        // ws (4,10,384)
  float* outvec;   // ws (4,10,384)
  float* xw;       // ws (4,10,384)
  float* simbuf;   // ws 2 * 85000 (two c-partials, combined in softmax kernel)
};

__device__ __forceinline__ int hw_of(int s){ return s==0?6400: s==1?1600: s==2?400:100; }
__device__ __forceinline__ int simoff(int s){ return s==0?0: s==1?64000: s==2?80000:84000; }
__device__ __forceinline__ size_t voutoff(int s){ return s==0?(size_t)VOFF0: s==1?(size_t)VOFF1: s==2?(size_t)VOFF2:(size_t)VOFF3; }
__device__ __forceinline__ const float* fm_of(const Params& P, int s){ return s==0?P.fmap0: s==1?P.fmap1: s==2?P.fmap2:P.fmap3; }
__device__ __forceinline__ const float* po_of(const Params& P, int s){ return s==0?P.pos0: s==1?P.pos1: s==2?P.pos2:P.pos3; }
__device__ __forceinline__ const float* au_of(const Params& P, int s){ return s==0?P.audio0: s==1?P.audio1: s==2?P.audio2:P.audio3; }

// ---------------- A: per-(s,b) small GEMVs: a, cqk, cv, r(=Wqk^T cqk * SCALE), outvec ----------------
__global__ __launch_bounds__(384) void k_pre(Params P) {
  const int s = blockIdx.x / BT, b = blockIdx.x % BT;
  const int tid = threadIdx.x;
  __shared__ float aud[CTXC], ctxv[CC], ctxpe[CC], cqk[DH], cvv[DH];
  const float* audio = au_of(P, s);
  if (tid < CTXC) aud[tid] = audio[b*CTXC + tid];
  __syncthreads();
  {
    float acc = P.ctx_proj_b[s*CC + tid];
    const float* wrow = P.ctx_proj_w + (size_t)(s*CC + tid)*CTXC;
    #pragma unroll 8
    for (int k = 0; k < CTXC; ++k) acc += wrow[k]*aud[k];
    ctxv[tid] = acc;
    ctxpe[tid] = acc + P.pos_emb[(s*5 + (b%5))*CC + tid];
  }
  __syncthreads();
  if (tid < DH) {
    float q = 0.f, v = 0.f;
    const float* wq = P.ctx_qk_w + (size_t)(s*DH + tid)*CC;
    const float* wv = P.ctx_v_w  + (size_t)(s*DH + tid)*CC;
    #pragma unroll 4
    for (int c = 0; c < CC; ++c) { q += wq[c]*ctxpe[c]; v += wv[c]*ctxv[c]; }
    cqk[tid] = q; cvv[tid] = v;
  }
  __syncthreads();
  {
    float rr = 0.f, ov = P.out_b[s*CC + tid];
    const float* wqk = P.qk_w + (size_t)s*DH*CC + tid;        // [d][tid], stride CC
    const float* wo  = P.out_w + (size_t)(s*CC + tid)*DH;
    #pragma unroll 4
    for (int d = 0; d < DH; ++d) { rr += wqk[(size_t)d*CC]*cqk[d]; ov += wo[d]*cvv[d]; }
    P.r[(s*BT+b)*CC + tid] = rr * SCALE_F;
    P.outvec[(s*BT+b)*CC + tid] = ov;
  }
}

// ---------------- E: broadcast-fill vout (out[b,c,:,:] = outvec[s,b,c]) ----------------
__global__ __launch_bounds__(128) void k_fill(Params P) {
  const int row = blockIdx.x;            // 0 .. 15360
  const int s = row / 3840, local = row % 3840;
  const int HW = hw_of(s);
  const float val = P.outvec[s*3840 + local];
  float* dst = P.out + voutoff(s) + (size_t)local*HW;
  const float4 v4 = {val, val, val, val};
  for (int i = threadIdx.x*4; i < HW; i += 128*4)
    *(float4*)(dst + i) = v4;
}

// ---------------- B: sim[b,i] = sum_c (x+pos)[b,c,i] * r[b,c]  (c split in 2 parts) ----------------
__global__ __launch_bounds__(256) void k_sim(Params P) {
  int bid = blockIdx.x;
  const int part = (bid >= 350) ? 1 : 0;
  bid -= part*350;
  int s, local, cb, HW;
  if (bid < 250)      { s=0; local=bid;      cb=25; HW=6400; }
  else if (bid < 320) { s=1; local=bid-250;  cb=7;  HW=1600; }
  else if (bid < 340) { s=2; local=bid-320;  cb=2;  HW=400;  }
  else                { s=3; local=bid-340;  cb=1;  HW=100;  }
  const int b = local / cb, chunk = local % cb;
  const int tid = threadIdx.x;
  const int c0 = part * 192;

  __shared__ float rs[192];
  const float* rrow = P.r + (s*BT+b)*CC + c0;
  if (tid < 192) rs[tid] = rrow[tid];
  __syncthreads();

  const int i = chunk*256 + tid;
  if (i < HW) {
    const float* xp = fm_of(P, s) + ((size_t)b*CC + c0)*HW + i;
    const float* pp = po_of(P, s) + ((size_t)b*CC + c0)*HW + i;
    float acc = 0.f;
    #pragma unroll 8
    for (int c = 0; c < 192; ++c)
      acc += (xp[(size_t)c*HW] + pp[(size_t)c*HW]) * rs[c];
    P.simbuf[part*SIM_TOT + simoff(s) + b*HW + i] = acc;
  }
}

// ---------------- C1: combine partials + softmax in place over i, per (s,b) ----------------
__global__ __launch_bounds__(256) void k_softmax(Params P) {
  const int s = blockIdx.x / BT, b = blockIdx.x % BT;
  const int HW = hw_of(s);
  float* sim  = P.simbuf + simoff(s) + b*HW;
  const float* sim2 = sim + SIM_TOT;
  const int tid = threadIdx.x;
  const int wid = tid >> 6, lane = tid & 63;
  __shared__ float red[4], red2[4];

  // pass 1: combine c-partials, track max (each thread owns its own i's throughout)
  float m = -1e30f;
  for (int i = tid; i < HW; i += 256) { float v = sim[i] + sim2[i]; sim[i] = v; m = fmaxf(m, v); }
  #pragma unroll
  for (int off = 32; off; off >>= 1) m = fmaxf(m, __shfl_down(m, off));
  if (lane == 0) red[wid] = m;
  __syncthreads();
  if (tid == 0) { float mm = red[0]; for (int w2 = 1; w2 < 4; ++w2) mm = fmaxf(mm, red[w2]); red[0] = mm; }
  __syncthreads();
  m = red[0];

  // pass 2: sum of exp
  float sum = 0.f;
  for (int i = tid; i < HW; i += 256) sum += expf(sim[i] - m);
  #pragma unroll
  for (int off = 32; off; off >>= 1) sum += __shfl_down(sum, off);
  if (lane == 0) red2[wid] = sum;
  __syncthreads();
  if (tid == 0) { float ss = red2[0]; for (int w2 = 1; w2 < 4; ++w2) ss += red2[w2]; red2[0] = ss; }
  __syncthreads();
  const float invS = 1.f / red2[0];

  // pass 3: normalized weights in place
  for (int i = tid; i < HW; i += 256) sim[i] = expf(sim[i] - m) * invS;
}

// ---------------- C2: xw[s,b,c] = sum_i w[b,i] * x[b,c,i]  (one wave per c) ----------------
__global__ __launch_bounds__(256) void k_xw(Params P) {
  const int bid = blockIdx.x;
  const int sb = bid / 96, ct = bid % 96;
  const int s = sb / BT, b = sb % BT;
  const int HW = hw_of(s);
  const int wid = threadIdx.x >> 6, lane = threadIdx.x & 63;
  const int c = ct*4 + wid;
  const float* xrow = fm_of(P, s) + ((size_t)(b*CC + c))*HW;
  const float* wrow = P.simbuf + simoff(s) + b*HW;
  float ax=0.f, ay=0.f, az=0.f, aw=0.f;
  #pragma unroll 4
  for (int i0 = lane*4; i0 < HW; i0 += 256) {
    const float4 x4 = *(const float4*)(xrow + i0);
    const float4 w4 = *(const float4*)(wrow + i0);
    ax += x4.x*w4.x; ay += x4.y*w4.y; az += x4.z*w4.z; aw += x4.w*w4.w;
  }
  float acc = (ax + ay) + (az + aw);
  #pragma unroll
  for (int off = 32; off; off >>= 1) acc += __shfl_down(acc, off);
  if (lane == 0) P.xw[(s*BT+b)*CC + c] = acc;
}

// ---------------- D: ctxo = Wv @ xw; aout = Wco @ ctxo + bco ----------------
__global__ __launch_bounds__(384) void k_post(Params P) {
  const int s = blockIdx.x / BT, b = blockIdx.x % BT;
  const int tid = threadIdx.x;
  __shared__ float xws[CC], ctxo[DH];
  xws[tid] = P.xw[(s*BT+b)*CC + tid];
  __syncthreads();
  if (tid < DH) {
    float acc = 0.f;
    const float* wv = P.v_w + (size_t)(s*DH + tid)*CC;
    #pragma unroll 4
    for (int c = 0; c < CC; ++c) acc += wv[c]*xws[c];
    ctxo[tid] = acc;
  }
  __syncthreads();
  float ao = P.ctx_out_b[s*CC + tid];
  const float* wco = P.ctx_out_w + (size_t)(s*CC + tid)*DH;
  #pragma unroll 4
  for (int d = 0; d < DH; ++d) ao += wco[d]*ctxo[d];
  P.out[(size_t)AOUT_OFF + (s*BT+b)*CC + tid] = ao;
}

extern "C" void kernel_launch(void* const* d_in, const int* in_sizes, int n_in,
                              void* d_out, int out_size, void* d_ws, size_t ws_size,
                              hipStream_t stream) {
  Params P;
  P.fmap0 = (const float*)d_in[0];  P.pos0 = (const float*)d_in[1];  P.audio0 = (const float*)d_in[2];
  P.fmap1 = (const float*)d_in[3];  P.pos1 = (const float*)d_in[4];  P.audio1 = (const float*)d_in[5];
  P.fmap2 = (const float*)d_in[6];  P.pos2 = (const float*)d_in[7];  P.audio2 = (const float*)d_in[8];
  P.fmap3 = (const float*)d_in[9];  P.pos3 = (const float*)d_in[10]; P.audio3 = (const float*)d_in[11];
  P.ctx_proj_w = (const float*)d_in[12]; P.ctx_proj_b = (const float*)d_in[13];
  P.pos_emb = (const float*)d_in[14];
  P.qk_w = (const float*)d_in[15];  P.ctx_qk_w = (const float*)d_in[16];
  P.v_w = (const float*)d_in[17];   P.ctx_v_w = (const float*)d_in[18];
  P.out_w = (const float*)d_in[19]; P.out_b = (const float*)d_in[20];
  P.ctx_out_w = (const float*)d_in[21]; P.ctx_out_b = (const float*)d_in[22];
  P.out = (float*)d_out;

  float* ws = (float*)d_ws;
  P.r      = ws;                 // 15360
  P.outvec = ws + 15360;         // 15360
  P.xw     = ws + 30720;         // 15360
  P.simbuf = ws + 46080;         // 2 * 85000

  k_pre    <<<NS*BT, 384, 0, stream>>>(P);
  k_fill   <<<15360, 128, 0, stream>>>(P);   // only depends on outvec
  k_sim    <<<700,   256, 0, stream>>>(P);
  k_softmax<<<NS*BT, 256, 0, stream>>>(P);
  k_xw     <<<3840,  256, 0, stream>>>(P);
  k_post   <<<NS*BT, 384, 0, stream>>>(P);
}